// Round 12
// baseline (40.748 us; speedup 1.0000x reference)
//
#include <hip/hip_runtime.h>

// InvariantPolynomial: out = sum_e xl[oi[e]] * xr[e] * f(|pos_e|)
// f depends only on d=|pos| (sh[:,:1]==1); 2048-entry linear LUT over [0,5].
//
// R12: R6 structure and LOAD ORDER (all independent loads issued together,
// gathers strictly after -- R11 lesson: putting gathers before the stream
// loads serializes the stream behind the cold oi load, +12us), with EPT=4
// (1954 blocks, ~2x waves/CU vs R6). Completes the {EPT x ordering} matrix:
//   R6  = EPT8 + good order = 28.0
//   R11 = EPT4 + bad  order = 40.5
//   R12 = EPT4 + good order = ?   (neutral -> gather MSHR-bound, declare)
// No NT (R9 +11us), no scatter (R10 +90us), no fence (R2 +27us).
// ws layout: [0,8KB) float LUT.

#define TN    2048
#define DMAXF 5.0f
#define TPB   256
#define EPT   4
#define TILE  (TPB * EPT)   // 1024 edges per block

// 1/sqrt(E[silu(z)^2]); matched reference exactly (absmax 0.0, R1-R11)
__device__ __constant__ float kSiluCst = 1.6765581f;

__global__ __launch_bounds__(256) void build_lut_kernel(
    const float* __restrict__ W1, const float* __restrict__ W2,
    float* __restrict__ table, float* __restrict__ out)
{
    if (blockIdx.x == 0 && threadIdx.x == 0) out[0] = 0.0f;  // replay-safe reset

    // 32 lanes per LUT entry: lane k in [0,30) computes hidden unit k.
    int t = blockIdx.x * 256 + threadIdx.x;
    int entry = t >> 5;
    int k = t & 31;
    int kk = (k < 30) ? k : 29;

    float d  = (float)entry * (DMAXF / (float)TN);
    float t6 = 6.0f * d;                      // gaussian centers at t6 = 1..20
    const float w1scale = 1.0f / (1.12f * sqrtf(20.0f));

    float a = 0.0f;
    #pragma unroll
    for (int j = 0; j < 20; ++j) {
        float df = t6 - (float)(j + 1);
        float e  = __expf(-df * df);
        a = fmaf(e * w1scale, W1[j * 30 + kk], a);
    }
    float s = a / (1.0f + __expf(-a));        // silu

    float w2s = 0.0f;
    #pragma unroll
    for (int c = 0; c < 5; ++c) w2s += W2[kk * 5 + c];

    float contrib = (k < 30) ? s * w2s * (kSiluCst / sqrtf(30.0f)) : 0.0f;

    #pragma unroll
    for (int m = 16; m > 0; m >>= 1) contrib += __shfl_xor(contrib, m, 32);

    if (k == 0 && entry < TN) table[entry] = contrib;
}

__global__ __launch_bounds__(TPB) void edge_sum_kernel(
    const float* __restrict__ pos, const float* __restrict__ xr,
    const float* __restrict__ xl, const int* __restrict__ oi,
    const float* __restrict__ table, float* __restrict__ out, int E)
{
    __shared__ float lut[TN];
    __shared__ double swv[TPB / 64];

    const int  tid   = threadIdx.x;
    const long tile0 = (long)blockIdx.x * TILE;
    const int  rem   = (int)min((long)TILE, (long)E - tile0);
    const int  e0    = tid * EPT;
    const bool full  = (e0 + EPT <= rem);

    // ---- all independent loads issued back-to-back (R6 order) ----
    int4 O; float4 P0, P1, P2, X;
    if (full) {
        const long g0 = tile0 + e0;
        const float4* p4 = (const float4*)(pos + g0 * 3);
        O  = *(const int4*)(oi + g0);
        P0 = p4[0]; P1 = p4[1]; P2 = p4[2];
        X  = *(const float4*)(xr + g0);
    }

    // ---- gathers: dependent only on O; stream loads remain in flight ----
    float xlv[EPT];
    if (full) {
        xlv[0] = xl[O.x]; xlv[1] = xl[O.y]; xlv[2] = xl[O.z]; xlv[3] = xl[O.w];
    }

    {   // stage 8KB LUT (2 float4/thread; table is L2/L3-hot)
        const float4* t4 = (const float4*)table;
        float4* l4 = (float4*)lut;
        l4[tid]       = t4[tid];
        l4[tid + TPB] = t4[tid + TPB];
    }
    __syncthreads();

    const float scale = (float)TN / DMAXF;
    const float umax  = (float)(TN - 1) - 1e-3f;
    double acc = 0.0;

    if (full) {
        float px[EPT] = {P0.x, P0.w, P1.z, P2.y};
        float py[EPT] = {P0.y, P1.x, P1.w, P2.z};
        float pz[EPT] = {P0.z, P1.y, P2.x, P2.w};
        float xrv[EPT] = {X.x, X.y, X.z, X.w};

        float fsum = 0.0f;
        #pragma unroll
        for (int j = 0; j < EPT; ++j) {
            float d  = sqrtf(fmaf(px[j], px[j], fmaf(py[j], py[j], pz[j] * pz[j])));
            float u  = fminf(d * scale, umax);
            int   i0 = (int)u;
            float fr = u - (float)i0;
            float f  = fmaf(fr, lut[i0 + 1] - lut[i0], lut[i0]);
            fsum = fmaf(f * xrv[j], xlv[j], fsum);
        }
        acc = (double)fsum;
    } else if (e0 < rem) {
        // guarded scalar tail (last block only)
        float fsum = 0.0f;
        for (int j = 0; j < EPT && e0 + j < rem; ++j) {
            long  ge = tile0 + e0 + j;
            float x = pos[3 * ge], y = pos[3 * ge + 1], z = pos[3 * ge + 2];
            float d  = sqrtf(fmaf(x, x, fmaf(y, y, z * z)));
            float u  = fminf(d * scale, umax);
            int   i0 = (int)u;
            float fr = u - (float)i0;
            float f  = fmaf(fr, lut[i0 + 1] - lut[i0], lut[i0]);
            fsum = fmaf(f * xr[ge], xl[oi[ge]], fsum);
        }
        acc = (double)fsum;
    }

    // deterministic block reduction (wave shfl + LDS across 4 waves)
    #pragma unroll
    for (int off = 32; off > 0; off >>= 1) acc += __shfl_down(acc, off);
    int lane = tid & 63, wv = tid >> 6;
    if (lane == 0) swv[wv] = acc;
    __syncthreads();
    if (tid == 0) {
        double bsum = (swv[0] + swv[1]) + (swv[2] + swv[3]);
        atomicAdd(out, (float)bsum);   // ~1954 atomics to one line: negligible
    }
}

extern "C" void kernel_launch(void* const* d_in, const int* in_sizes, int n_in,
                              void* d_out, int out_size, void* d_ws, size_t ws_size,
                              hipStream_t stream) {
    const float* pos = (const float*)d_in[0];   // [E,3]
    const float* xr  = (const float*)d_in[1];   // [E,1]
    const float* xl  = (const float*)d_in[2];   // [N,1]
    const float* W1  = (const float*)d_in[3];   // [20,30]
    const float* W2  = (const float*)d_in[4];   // [30,5]
    const int*   oi  = (const int*)d_in[5];     // [E]
    float* out = (float*)d_out;

    int E = in_sizes[1];
    int nblk = (E + TILE - 1) / TILE;           // 1954 for E=2M

    float* table = (float*)d_ws;

    hipLaunchKernelGGL(build_lut_kernel, dim3((TN * 32) / 256), dim3(256), 0, stream,
                       W1, W2, table, out);
    hipLaunchKernelGGL(edge_sum_kernel, dim3(nblk), dim3(TPB), 0, stream,
                       pos, xr, xl, oi, table, out, E);
}

// Round 13
// 36.495 us; speedup vs baseline: 1.1165x; 1.1165x over previous
//
#include <hip/hip_runtime.h>

// InvariantPolynomial: out = sum_e xl[oi[e]] * xr[e] * f(|pos_e|)
// f depends only on d=|pos| (sh[:,:1]==1); 2048-entry linear LUT over [0,5].
//
// R13: SPLIT-PHASE (probe + candidate fix in one):
//  K1 build_lut: LUT + zero out
//  K2 val_kernel: val[e] = xr[e]*f(|pos_e|) -- PURE STREAM, no oi/xl/atomics.
//     Measures cold-stream roofline (should be ~6-7us at BW ceiling).
//  K3 gather_kernel: out += val[e]*xl[oi[e]] -- PURE GATHER at max MLP.
//     If MSHR-bound: ~18us (neutral overall). If chain-coupling was the
//     wall: ~5-7us (win).
// Lessons kept: no loads before LDS staging (in-order vmcnt serializes the
// ds_write behind gathers: R11/R12 +12us), no NT (R9), no scatter-atomics
// (R10), no threadfence (R2), no per-block LUT rebuild (R5).
// ws layout: [0,8KB) float LUT; [8KB, 8KB+4*E) float val.  (~8MB)

#define TN    2048
#define DMAXF 5.0f
#define TPB   256
#define EPT   8
#define TILE  (TPB * EPT)   // 2048 edges per block

// 1/sqrt(E[silu(z)^2]); matched reference exactly (absmax 0.0, R1-R12)
__device__ __constant__ float kSiluCst = 1.6765581f;

__global__ __launch_bounds__(256) void build_lut_kernel(
    const float* __restrict__ W1, const float* __restrict__ W2,
    float* __restrict__ table, float* __restrict__ out)
{
    if (blockIdx.x == 0 && threadIdx.x == 0) out[0] = 0.0f;  // replay-safe reset

    int t = blockIdx.x * 256 + threadIdx.x;
    int entry = t >> 5;
    int k = t & 31;
    int kk = (k < 30) ? k : 29;

    float d  = (float)entry * (DMAXF / (float)TN);
    float t6 = 6.0f * d;                      // gaussian centers at t6 = 1..20
    const float w1scale = 1.0f / (1.12f * sqrtf(20.0f));

    float a = 0.0f;
    #pragma unroll
    for (int j = 0; j < 20; ++j) {
        float df = t6 - (float)(j + 1);
        float e  = __expf(-df * df);
        a = fmaf(e * w1scale, W1[j * 30 + kk], a);
    }
    float s = a / (1.0f + __expf(-a));        // silu

    float w2s = 0.0f;
    #pragma unroll
    for (int c = 0; c < 5; ++c) w2s += W2[kk * 5 + c];

    float contrib = (k < 30) ? s * w2s * (kSiluCst / sqrtf(30.0f)) : 0.0f;

    #pragma unroll
    for (int m = 16; m > 0; m >>= 1) contrib += __shfl_xor(contrib, m, 32);

    if (k == 0 && entry < TN) table[entry] = contrib;
}

// K2: pure stream. val[e] = xr[e] * f(|pos_e|). No gather, no reduce.
__global__ __launch_bounds__(TPB) void val_kernel(
    const float* __restrict__ pos, const float* __restrict__ xr,
    const float* __restrict__ table, float* __restrict__ val, int E)
{
    __shared__ float lut[TN];
    const int tid = threadIdx.x;

    {   // LDS staging FIRST, before any other vmem (in-order vmcnt lesson)
        const float4* t4 = (const float4*)table;
        float4* l4 = (float4*)lut;
        l4[tid]       = t4[tid];
        l4[tid + TPB] = t4[tid + TPB];
    }
    __syncthreads();

    const float scale = (float)TN / DMAXF;
    const float umax  = (float)(TN - 1) - 1e-3f;

    const long tile0 = (long)blockIdx.x * TILE;
    const int  rem   = (int)min((long)TILE, (long)E - tile0);
    const int  e0    = tid * EPT;

    if (e0 + EPT <= rem) {
        const long g0 = tile0 + e0;
        const float4* p4 = (const float4*)(pos + g0 * 3);
        float4 P0 = p4[0], P1 = p4[1], P2 = p4[2], P3 = p4[3], P4 = p4[4], P5 = p4[5];
        float4 X0 = ((const float4*)(xr + g0))[0];
        float4 X1 = ((const float4*)(xr + g0))[1];

        float px[EPT] = {P0.x, P0.w, P1.z, P2.y, P3.x, P3.w, P4.z, P5.y};
        float py[EPT] = {P0.y, P1.x, P1.w, P2.z, P3.y, P4.x, P4.w, P5.z};
        float pz[EPT] = {P0.z, P1.y, P2.x, P2.w, P3.z, P4.y, P5.x, P5.w};
        float xrv[EPT] = {X0.x, X0.y, X0.z, X0.w, X1.x, X1.y, X1.z, X1.w};

        float v[EPT];
        #pragma unroll
        for (int j = 0; j < EPT; ++j) {
            float d  = sqrtf(fmaf(px[j], px[j], fmaf(py[j], py[j], pz[j] * pz[j])));
            float u  = fminf(d * scale, umax);
            int   i0 = (int)u;
            float fr = u - (float)i0;
            float f  = fmaf(fr, lut[i0 + 1] - lut[i0], lut[i0]);
            v[j] = f * xrv[j];
        }
        float4* o4 = (float4*)(val + g0);
        o4[0] = make_float4(v[0], v[1], v[2], v[3]);
        o4[1] = make_float4(v[4], v[5], v[6], v[7]);
    } else if (e0 < rem) {
        for (int j = 0; j < EPT && e0 + j < rem; ++j) {
            long  ge = tile0 + e0 + j;
            float x = pos[3 * ge], y = pos[3 * ge + 1], z = pos[3 * ge + 2];
            float d  = sqrtf(fmaf(x, x, fmaf(y, y, z * z)));
            float u  = fminf(d * scale, umax);
            int   i0 = (int)u;
            float fr = u - (float)i0;
            float f  = fmaf(fr, lut[i0 + 1] - lut[i0], lut[i0]);
            val[ge] = f * xr[ge];
        }
    }
}

// K3: pure gather-reduce. out += sum_e val[e] * xl[oi[e]].
__global__ __launch_bounds__(TPB) void gather_kernel(
    const float* __restrict__ val, const int* __restrict__ oi,
    const float* __restrict__ xl, float* __restrict__ out, int E)
{
    __shared__ double swv[TPB / 64];

    const int  tid   = threadIdx.x;
    const long tile0 = (long)blockIdx.x * TILE;
    const int  rem   = (int)min((long)TILE, (long)E - tile0);
    const int  e0    = tid * EPT;
    double acc = 0.0;

    if (e0 + EPT <= rem) {
        const long g0 = tile0 + e0;
        const int4*   o4 = (const int4*)(oi + g0);
        const float4* v4 = (const float4*)(val + g0);
        int4   O0 = o4[0], O1 = o4[1];
        float4 V0 = v4[0], V1 = v4[1];

        // 8 independent gathers in flight per thread (max MLP)
        float xlv[EPT];
        xlv[0] = xl[O0.x]; xlv[1] = xl[O0.y]; xlv[2] = xl[O0.z]; xlv[3] = xl[O0.w];
        xlv[4] = xl[O1.x]; xlv[5] = xl[O1.y]; xlv[6] = xl[O1.z]; xlv[7] = xl[O1.w];

        float vv[EPT] = {V0.x, V0.y, V0.z, V0.w, V1.x, V1.y, V1.z, V1.w};
        float fsum = 0.0f;
        #pragma unroll
        for (int j = 0; j < EPT; ++j) fsum = fmaf(vv[j], xlv[j], fsum);
        acc = (double)fsum;
    } else if (e0 < rem) {
        float fsum = 0.0f;
        for (int j = 0; j < EPT && e0 + j < rem; ++j) {
            long ge = tile0 + e0 + j;
            fsum = fmaf(val[ge], xl[oi[ge]], fsum);
        }
        acc = (double)fsum;
    }

    // deterministic block reduction (wave shfl + LDS across 4 waves)
    #pragma unroll
    for (int off = 32; off > 0; off >>= 1) acc += __shfl_down(acc, off);
    int lane = tid & 63, wv = tid >> 6;
    if (lane == 0) swv[wv] = acc;
    __syncthreads();
    if (tid == 0) {
        double bsum = (swv[0] + swv[1]) + (swv[2] + swv[3]);
        atomicAdd(out, (float)bsum);   // ~977 atomics to one line: negligible
    }
}

extern "C" void kernel_launch(void* const* d_in, const int* in_sizes, int n_in,
                              void* d_out, int out_size, void* d_ws, size_t ws_size,
                              hipStream_t stream) {
    const float* pos = (const float*)d_in[0];   // [E,3]
    const float* xr  = (const float*)d_in[1];   // [E,1]
    const float* xl  = (const float*)d_in[2];   // [N,1]
    const float* W1  = (const float*)d_in[3];   // [20,30]
    const float* W2  = (const float*)d_in[4];   // [30,5]
    const int*   oi  = (const int*)d_in[5];     // [E]
    float* out = (float*)d_out;

    int E = in_sizes[1];
    int nblk = (E + TILE - 1) / TILE;           // 977 for E=2M

    float* table = (float*)d_ws;
    float* val   = (float*)((char*)d_ws + (size_t)TN * sizeof(float));

    hipLaunchKernelGGL(build_lut_kernel, dim3((TN * 32) / 256), dim3(256), 0, stream,
                       W1, W2, table, out);
    hipLaunchKernelGGL(val_kernel, dim3(nblk), dim3(TPB), 0, stream,
                       pos, xr, table, val, E);
    hipLaunchKernelGGL(gather_kernel, dim3(nblk), dim3(TPB), 0, stream,
                       val, oi, xl, out, E);
}

// Round 14
// 28.567 us; speedup vs baseline: 1.4264x; 1.2775x over previous
//
#include <hip/hip_runtime.h>

// InvariantPolynomial: out = sum_e xl[oi[e]] * xr[e] * f(|pos_e|)
// f depends only on d=|pos| (sh[:,:1]==1); 2048-entry linear LUT over [0,5].
//
// R14 = R6 (28.0us baseline: 2 dispatches, EPT=8, LUT-LDS staged first)
// with ONE change: xl gathers use relaxed agent-scope atomic loads ->
// global_load sc0 -> L1 BYPASS. Model: per-CU L1 miss path (~7cy/miss,
// MSHR alloc+fill+replay) x 2M random gather misses = the invariant ~27us
// wall seen in R1/R3/R4/R6/R12. xl is L2-resident (500KB/4MB); bypass
// skips the pointless L1 allocate/replay. Streams keep caching loads
// (R9: NT on streams = +11us).
// Kept lessons: LDS staging before any long-latency vmem (R11/R12 +12us),
// no scatter atomics (R10 +77us), no threadfence (R2 +27us), no per-block
// LUT rebuild (R5 +15us).
// ws layout: [0,8KB) float LUT.

#define TN    2048
#define DMAXF 5.0f
#define TPB   256
#define EPT   8
#define TILE  (TPB * EPT)   // 2048 edges per block

// 1/sqrt(E[silu(z)^2]); matched reference exactly (absmax 0.0, R1-R13)
__device__ __constant__ float kSiluCst = 1.6765581f;

__global__ __launch_bounds__(256) void build_lut_kernel(
    const float* __restrict__ W1, const float* __restrict__ W2,
    float* __restrict__ table, float* __restrict__ out)
{
    if (blockIdx.x == 0 && threadIdx.x == 0) out[0] = 0.0f;  // replay-safe reset

    // 32 lanes per LUT entry: lane k in [0,30) computes hidden unit k.
    int t = blockIdx.x * 256 + threadIdx.x;
    int entry = t >> 5;
    int k = t & 31;
    int kk = (k < 30) ? k : 29;

    float d  = (float)entry * (DMAXF / (float)TN);
    float t6 = 6.0f * d;                      // gaussian centers at t6 = 1..20
    const float w1scale = 1.0f / (1.12f * sqrtf(20.0f));

    float a = 0.0f;
    #pragma unroll
    for (int j = 0; j < 20; ++j) {
        float df = t6 - (float)(j + 1);
        float e  = __expf(-df * df);
        a = fmaf(e * w1scale, W1[j * 30 + kk], a);
    }
    float s = a / (1.0f + __expf(-a));        // silu

    float w2s = 0.0f;
    #pragma unroll
    for (int c = 0; c < 5; ++c) w2s += W2[kk * 5 + c];

    float contrib = (k < 30) ? s * w2s * (kSiluCst / sqrtf(30.0f)) : 0.0f;

    #pragma unroll
    for (int m = 16; m > 0; m >>= 1) contrib += __shfl_xor(contrib, m, 32);

    if (k == 0 && entry < TN) table[entry] = contrib;
}

__global__ __launch_bounds__(TPB) void edge_sum_kernel(
    const float* __restrict__ pos, const float* __restrict__ xr,
    const float* __restrict__ xl, const int* __restrict__ oi,
    const float* __restrict__ table, float* __restrict__ out, int E)
{
    __shared__ float lut[TN];
    __shared__ double swv[TPB / 64];

    const int tid = threadIdx.x;

    {   // stage 8KB LUT FIRST (in-order vmcnt: nothing long-latency before this)
        const float4* t4 = (const float4*)table;
        float4* l4 = (float4*)lut;
        l4[tid]       = t4[tid];
        l4[tid + TPB] = t4[tid + TPB];
    }
    __syncthreads();

    const float scale = (float)TN / DMAXF;
    const float umax  = (float)(TN - 1) - 1e-3f;

    const long tile0 = (long)blockIdx.x * TILE;
    const int  rem   = (int)min((long)TILE, (long)E - tile0);
    const int  e0    = tid * EPT;
    double acc = 0.0;

    if (e0 + EPT <= rem) {
        const long g0 = tile0 + e0;
        const float4* p4 = (const float4*)(pos + g0 * 3);
        float4 P0 = p4[0], P1 = p4[1], P2 = p4[2], P3 = p4[3], P4 = p4[4], P5 = p4[5];
        const float4* x4 = (const float4*)(xr + g0);
        float4 X0 = x4[0], X1 = x4[1];
        const int4* o4 = (const int4*)(oi + g0);
        int4 O0 = o4[0], O1 = o4[1];

        // xl gathers: L1-BYPASS (sc0) via relaxed agent-scope atomic loads.
        // xl is L2-resident; skip L1 MSHR alloc/replay on guaranteed misses.
        float xlv[EPT];
        xlv[0] = __hip_atomic_load(&xl[O0.x], __ATOMIC_RELAXED, __HIP_MEMORY_SCOPE_AGENT);
        xlv[1] = __hip_atomic_load(&xl[O0.y], __ATOMIC_RELAXED, __HIP_MEMORY_SCOPE_AGENT);
        xlv[2] = __hip_atomic_load(&xl[O0.z], __ATOMIC_RELAXED, __HIP_MEMORY_SCOPE_AGENT);
        xlv[3] = __hip_atomic_load(&xl[O0.w], __ATOMIC_RELAXED, __HIP_MEMORY_SCOPE_AGENT);
        xlv[4] = __hip_atomic_load(&xl[O1.x], __ATOMIC_RELAXED, __HIP_MEMORY_SCOPE_AGENT);
        xlv[5] = __hip_atomic_load(&xl[O1.y], __ATOMIC_RELAXED, __HIP_MEMORY_SCOPE_AGENT);
        xlv[6] = __hip_atomic_load(&xl[O1.z], __ATOMIC_RELAXED, __HIP_MEMORY_SCOPE_AGENT);
        xlv[7] = __hip_atomic_load(&xl[O1.w], __ATOMIC_RELAXED, __HIP_MEMORY_SCOPE_AGENT);

        float px[EPT] = {P0.x, P0.w, P1.z, P2.y, P3.x, P3.w, P4.z, P5.y};
        float py[EPT] = {P0.y, P1.x, P1.w, P2.z, P3.y, P4.x, P4.w, P5.z};
        float pz[EPT] = {P0.z, P1.y, P2.x, P2.w, P3.z, P4.y, P5.x, P5.w};
        float xrv[EPT] = {X0.x, X0.y, X0.z, X0.w, X1.x, X1.y, X1.z, X1.w};

        float fsum = 0.0f;
        #pragma unroll
        for (int j = 0; j < EPT; ++j) {
            float d  = sqrtf(fmaf(px[j], px[j], fmaf(py[j], py[j], pz[j] * pz[j])));
            float u  = fminf(d * scale, umax);
            int   i0 = (int)u;
            float fr = u - (float)i0;
            float f  = fmaf(fr, lut[i0 + 1] - lut[i0], lut[i0]);
            fsum = fmaf(f * xrv[j], xlv[j], fsum);
        }
        acc = (double)fsum;
    } else if (e0 < rem) {
        // guarded scalar tail (last block only)
        float fsum = 0.0f;
        for (int j = 0; j < EPT && e0 + j < rem; ++j) {
            long  ge = tile0 + e0 + j;
            float x = pos[3 * ge], y = pos[3 * ge + 1], z = pos[3 * ge + 2];
            float d  = sqrtf(fmaf(x, x, fmaf(y, y, z * z)));
            float u  = fminf(d * scale, umax);
            int   i0 = (int)u;
            float fr = u - (float)i0;
            float f  = fmaf(fr, lut[i0 + 1] - lut[i0], lut[i0]);
            float xlj = __hip_atomic_load(&xl[oi[ge]], __ATOMIC_RELAXED,
                                          __HIP_MEMORY_SCOPE_AGENT);
            fsum = fmaf(f * xr[ge], xlj, fsum);
        }
        acc = (double)fsum;
    }

    // deterministic block reduction (wave shfl + LDS across 4 waves)
    #pragma unroll
    for (int off = 32; off > 0; off >>= 1) acc += __shfl_down(acc, off);
    int lane = tid & 63, wv = tid >> 6;
    if (lane == 0) swv[wv] = acc;
    __syncthreads();
    if (tid == 0) {
        double bsum = (swv[0] + swv[1]) + (swv[2] + swv[3]);
        atomicAdd(out, (float)bsum);   // ~977 atomics to one line: negligible
    }
}

extern "C" void kernel_launch(void* const* d_in, const int* in_sizes, int n_in,
                              void* d_out, int out_size, void* d_ws, size_t ws_size,
                              hipStream_t stream) {
    const float* pos = (const float*)d_in[0];   // [E,3]
    const float* xr  = (const float*)d_in[1];   // [E,1]
    const float* xl  = (const float*)d_in[2];   // [N,1]
    const float* W1  = (const float*)d_in[3];   // [20,30]
    const float* W2  = (const float*)d_in[4];   // [30,5]
    const int*   oi  = (const int*)d_in[5];     // [E]
    float* out = (float*)d_out;

    int E = in_sizes[1];
    int nblk = (E + TILE - 1) / TILE;           // 977 for E=2M

    float* table = (float*)d_ws;

    hipLaunchKernelGGL(build_lut_kernel, dim3((TN * 32) / 256), dim3(256), 0, stream,
                       W1, W2, table, out);
    hipLaunchKernelGGL(edge_sum_kernel, dim3(nblk), dim3(TPB), 0, stream,
                       pos, xr, xl, oi, table, out, E);
}